// Round 1
// baseline (299.431 us; speedup 1.0000x reference)
//
#include <hip/hip_runtime.h>

// SpecAugment: B=64, C=2, F=128, T=2048, fp32.
// out[b,c,f,t] = apply[b] ? (keep[b,f,t] ? spec : 0) + noise*0.01 : spec
// Memory-bound: spec+out always (268 MB), noise only for applied batches.

#define BB 64
#define CC 2
#define FF 128
#define TT 2048

__global__ __launch_bounds__(256) void specaug_kernel(
    const float* __restrict__ spec,
    const float* __restrict__ apply_u,
    const float* __restrict__ f_width_u,
    const float* __restrict__ f_start_u,
    const float* __restrict__ t_width_u,
    const float* __restrict__ t_start_u,
    const float* __restrict__ noise,
    float* __restrict__ out)
{
    // One float4 along T per thread. T/4 = 512 vecs per (b,c,f) row.
    const int vec = blockIdx.x * blockDim.x + threadIdx.x;
    const int tv  = vec & (TT / 4 - 1);      // 0..511
    const int row = vec >> 9;                // (b*C + c)*F + f
    const int f   = row & (FF - 1);
    const int b   = row >> 8;                // row / (C*F) with C=2, F=128
    const int t0  = tv << 2;

    const float4 s = ((const float4*)spec)[vec];
    float4 o;

    // b is wave-uniform (each wave spans 256 consecutive t within one row),
    // so this branch does not diverge and non-applied batches skip the
    // noise load entirely.
    if (apply_u[b] <= 0.5f) {
        // Frequency masks (no clamp on range; F - w >= 109 > 0 always).
        bool fmask = false;
        #pragma unroll
        for (int k = 0; k < 2; ++k) {
            const int   w   = (int)floorf(f_width_u[b * 2 + k] * 20.0f);
            const float rng = (float)(FF - w);
            const int   s0  = (int)floorf(f_start_u[b * 2 + k] * rng);
            fmask |= (f >= s0) & (f < s0 + w);
        }
        // Time masks (range clamped to >= 1).
        int ts0[2], tw[2];
        #pragma unroll
        for (int k = 0; k < 2; ++k) {
            const int   w   = (int)floorf(t_width_u[b * 2 + k] * 40.0f);
            const float rng = fmaxf((float)(TT - w), 1.0f);
            ts0[k] = (int)floorf(t_start_u[b * 2 + k] * rng);
            tw[k]  = w;
        }

        const float4 n = ((const float4*)noise)[vec];
        const float sv[4] = {s.x, s.y, s.z, s.w};
        const float nv[4] = {n.x, n.y, n.z, n.w};
        float ov[4];
        #pragma unroll
        for (int j = 0; j < 4; ++j) {
            const int t = t0 + j;
            bool tmask = false;
            #pragma unroll
            for (int k = 0; k < 2; ++k)
                tmask |= (t >= ts0[k]) & (t < ts0[k] + tw[k]);
            const bool keep = (!fmask) & (!tmask);
            ov[j] = (keep ? sv[j] : 0.0f) + nv[j] * 0.01f;
        }
        o = make_float4(ov[0], ov[1], ov[2], ov[3]);
    } else {
        o = s;
    }
    ((float4*)out)[vec] = o;
}

extern "C" void kernel_launch(void* const* d_in, const int* in_sizes, int n_in,
                              void* d_out, int out_size, void* d_ws, size_t ws_size,
                              hipStream_t stream) {
    const float* spec      = (const float*)d_in[0];
    const float* apply_u   = (const float*)d_in[1];
    const float* f_width_u = (const float*)d_in[2];
    const float* f_start_u = (const float*)d_in[3];
    const float* t_width_u = (const float*)d_in[4];
    const float* t_start_u = (const float*)d_in[5];
    const float* noise     = (const float*)d_in[6];
    float* out             = (float*)d_out;

    const int total_vecs = BB * CC * FF * (TT / 4);   // 8,388,608
    const int block = 256;
    const int grid  = total_vecs / block;             // 32,768

    specaug_kernel<<<grid, block, 0, stream>>>(
        spec, apply_u, f_width_u, f_start_u, t_width_u, t_start_u, noise, out);
}